// Round 1
// baseline (893.568 us; speedup 1.0000x reference)
//
#include <hip/hip_runtime.h>
#include <hip/hip_bf16.h>

// Problem constants (match reference)
#define E_DIM 512
#define D_DIM 512
#define A_DIM 256
#define B_SZ  64
#define T_SZ  4096
#define TT    32              // t-rows per tile (double-buffered)
#define NTB   (T_SZ / TT)     // 128 tiles per b
#define TPB   16              // tiles per persistent block
#define SLICES (NTB / TPB)    // 8 slices per b -> grid 64*8 = 512 blocks (2/CU)
#define LDT   (E_DIM + 8)     // LDS row stride (bf16 elems); +8 -> b128 reads 2-way max

typedef __bf16 bf16_t;
typedef bf16_t bf16x8 __attribute__((ext_vector_type(8)));
typedef float  f32x4  __attribute__((ext_vector_type(4)));

// round-to-nearest-even f32 -> bf16 bits
__device__ __forceinline__ unsigned short f2bf(float x) {
    union { float f; unsigned int u; } v; v.f = x;
    unsigned int u = v.u;
    return (unsigned short)((u + 0x7FFFu + ((u >> 16) & 1u)) >> 16);
}
__device__ __forceinline__ float bf2f(unsigned short h) {
    union { unsigned int u; float f; } v; v.u = ((unsigned int)h) << 16; return v.f;
}
__device__ __forceinline__ float tanh_fast(float x) {
    x = fminf(8.0f, fmaxf(-8.0f, x));            // exp(16) finite, avoids inf/inf
    float e = __expf(2.0f * x);
    return 1.0f - 2.0f * __builtin_amdgcn_rcpf(e + 1.0f);
}

// ---------------- Kernel 1: prep ----------------
// blocks 0..63   : dp[b][a] = b_enc[a] + sum_d dec[b][d]*W_dec[d][a]
//                  + zero ctx_acc[b][:] and S[b] (ws is re-poisoned per iter)
// blocks 64..127 : Wt[a][e] = bf16(W_enc[e][a])   (transposed, B-frag friendly)
__global__ __launch_bounds__(256) void prep_kernel(
    const float* __restrict__ dec, const float* __restrict__ W_enc,
    const float* __restrict__ b_enc, const float* __restrict__ W_dec,
    float* __restrict__ dp, unsigned short* __restrict__ Wt,
    float* __restrict__ ctx_acc, float* __restrict__ S)
{
    const int bid = blockIdx.x, tid = threadIdx.x;
    if (bid < B_SZ) {
        float s = b_enc[tid];
        const float* dr = dec + bid * D_DIM;
        #pragma unroll 8
        for (int d = 0; d < D_DIM; ++d)
            s = fmaf(dr[d], W_dec[d * A_DIM + tid], s);
        dp[bid * A_DIM + tid] = s;
        // zero the atomic accumulators for this b
        ctx_acc[bid * E_DIM + tid]       = 0.0f;
        ctx_acc[bid * E_DIM + 256 + tid] = 0.0f;
        if (tid == 0) S[bid] = 0.0f;
    } else {
        int base = (bid - B_SZ) * 2048;
        #pragma unroll
        for (int i = 0; i < 8; ++i) {
            int idx = base + tid + i * 256;       // idx = a*512 + e
            int a = idx >> 9, e = idx & 511;
            Wt[idx] = f2bf(W_enc[e * A_DIM + a]);
        }
    }
}

// ---------------- Kernel 2: main (persistent, double-buffered pipeline) -----
// 512 blocks (p = b*8 + slice), 512 threads (8 waves), 2 blocks/CU (LDS ~70KB).
// Each block walks 16 consecutive t-tiles of 32 rows. Per tile:
//   issue next-tile global loads -> GEMM (buf cur) -> scores -> exp -> context
//   -> cvt + ds_write staged regs into buf nxt.
// Context partials & softmax denom accumulate in registers across all 16 tiles;
// one atomicAdd per thread / per block at the end.
__global__ __launch_bounds__(512, 4) void attn_main(
    const float* __restrict__ enc, const unsigned short* __restrict__ Wt,
    const float* __restrict__ dpg, const float* __restrict__ vatt,
    float* __restrict__ u_out, float* __restrict__ ctx_acc,
    float* __restrict__ S)
{
    const int p = blockIdx.x;
    const int b = p >> 3, slice = p & 7;
    const int tid = threadIdx.x;

    __shared__ unsigned short tile[2][TT * LDT];  // 2 x 33,280 B
    __shared__ float spart[8][TT];                // 1 KB
    __shared__ float uu[TT];
    __shared__ float dp_s[A_DIM];
    __shared__ float vv[A_DIM];

    if (tid < A_DIM) {
        dp_s[tid] = dpg[b * A_DIM + tid];
        vv[tid]   = vatt[tid];
    }

    const int w = tid >> 6, lane = tid & 63;
    const int m16 = lane & 15, q = lane >> 4;

    // base of this block's 16-tile stream: contiguous 8 MB of enc
    const float4* src0 = (const float4*)(enc +
        ((size_t)b * T_SZ + (size_t)slice * TPB * TT) * E_DIM);
    // one tile = 32*512 f32 = 4096 float4; 8 float4 per thread

    // ---- prologue: stage tile 0 into buf 0 ----
    float4 r[8];
    #pragma unroll
    for (int it = 0; it < 8; ++it) r[it] = src0[tid + it * 512];
    #pragma unroll
    for (int it = 0; it < 8; ++it) {
        int idx = tid + it * 512;
        int rr = idx >> 7, cc = idx & 127;
        ushort4 h;
        h.x = f2bf(r[it].x); h.y = f2bf(r[it].y);
        h.z = f2bf(r[it].z); h.w = f2bf(r[it].w);
        *(ushort4*)&tile[0][rr * LDT + cc * 4] = h;
    }
    __syncthreads();

    float va0, va1, dv0, dv1;
    {
        int a0 = w * 32 + m16;
        va0 = vv[a0]; va1 = vv[a0 + 16];
        dv0 = dp_s[a0]; dv1 = dp_s[a0 + 16];
    }

    const unsigned short* WtW = Wt + (size_t)(w * 32) * E_DIM;

    float c_acc = 0.0f;   // context partial for col e = tid
    float sS    = 0.0f;   // exp-sum partial (tid < 32 only)

    for (int i = 0; i < TPB; ++i) {
        const int cur = i & 1, nxt = cur ^ 1;

        // issue next tile's loads now; they fly under GEMM+epilogue (~3 us)
        if (i + 1 < TPB) {
            const float4* srcn = src0 + (size_t)(i + 1) * 4096;
            #pragma unroll
            for (int it = 0; it < 8; ++it) r[it] = srcn[tid + it * 512];
        }

        // GEMM: M=32(t) x N=256(a) x K=512(e); wave w -> cols [w*32, w*32+32)
        f32x4 acc[2][2];
        #pragma unroll
        for (int mi = 0; mi < 2; ++mi)
            #pragma unroll
            for (int ni = 0; ni < 2; ++ni)
                acc[mi][ni] = (f32x4){0.f, 0.f, 0.f, 0.f};

        #pragma unroll 4
        for (int k0 = 0; k0 < E_DIM; k0 += 32) {
            const int ka = k0 + q * 8;
            bf16x8 afr0 = *(const bf16x8*)&tile[cur][(m16) * LDT + ka];
            bf16x8 afr1 = *(const bf16x8*)&tile[cur][(16 + m16) * LDT + ka];
            bf16x8 bfr0 = *(const bf16x8*)&WtW[(m16) * E_DIM + ka];
            bf16x8 bfr1 = *(const bf16x8*)&WtW[(16 + m16) * E_DIM + ka];
            acc[0][0] = __builtin_amdgcn_mfma_f32_16x16x32_bf16(afr0, bfr0, acc[0][0], 0, 0, 0);
            acc[0][1] = __builtin_amdgcn_mfma_f32_16x16x32_bf16(afr0, bfr1, acc[0][1], 0, 0, 0);
            acc[1][0] = __builtin_amdgcn_mfma_f32_16x16x32_bf16(afr1, bfr0, acc[1][0], 0, 0, 0);
            acc[1][1] = __builtin_amdgcn_mfma_f32_16x16x32_bf16(afr1, bfr1, acc[1][1], 0, 0, 0);
        }

        // scores: s_t = sum_a v[a]*tanh(proj + dp[a])  (b_att cancels in softmax)
        #pragma unroll
        for (int mi = 0; mi < 2; ++mi) {
            #pragma unroll
            for (int rr = 0; rr < 4; ++rr) {
                float pv = va0 * tanh_fast(acc[mi][0][rr] + dv0)
                         + va1 * tanh_fast(acc[mi][1][rr] + dv1);
                pv += __shfl_xor(pv, 1); pv += __shfl_xor(pv, 2);
                pv += __shfl_xor(pv, 4); pv += __shfl_xor(pv, 8);
                if (m16 == 0) spart[w][mi * 16 + q * 4 + rr] = pv;
            }
        }
        __syncthreads();                          // A: spart ready

        if (tid < TT) {
            float s = 0.f;
            #pragma unroll
            for (int w8 = 0; w8 < 8; ++w8) s += spart[w8][tid];
            float e = __expf(s);                  // |s| <= ~16 -> safe
            uu[tid] = e;
            sS += e;
            u_out[(size_t)b * T_SZ + (size_t)(slice * TPB + i) * TT + tid] = e;
        }
        __syncthreads();                          // B: uu ready

        // context partial from resident tile: col e = tid
        #pragma unroll 8
        for (int t = 0; t < TT; ++t)
            c_acc = fmaf(uu[t], bf2f(tile[cur][t * LDT + tid]), c_acc);

        // drain staged regs -> buf nxt (safe: all readers of nxt passed barrier A)
        if (i + 1 < TPB) {
            #pragma unroll
            for (int it = 0; it < 8; ++it) {
                int idx = tid + it * 512;
                int rr = idx >> 7, cc = idx & 127;
                ushort4 h;
                h.x = f2bf(r[it].x); h.y = f2bf(r[it].y);
                h.z = f2bf(r[it].z); h.w = f2bf(r[it].w);
                *(ushort4*)&tile[nxt][rr * LDT + cc * 4] = h;
            }
        }
        __syncthreads();                          // C: buf nxt staged
    }

    // one atomic per thread for context, one per block for the denom
    atomicAdd(&ctx_acc[(size_t)b * E_DIM + tid], c_acc);
    if (w == 0) {
        sS += __shfl_xor(sS, 1);  sS += __shfl_xor(sS, 2);
        sS += __shfl_xor(sS, 4);  sS += __shfl_xor(sS, 8);
        sS += __shfl_xor(sS, 16); sS += __shfl_xor(sS, 32);
        if (lane == 0) atomicAdd(&S[b], sS);
    }
}

// ---------------- Kernel 3: finalize (pure scaling) --------------------------
// grid (64, 4): block (b, j) scales quarter of the weights row; j==0 also ctx.
__global__ __launch_bounds__(256) void finalize_kernel(
    const float* __restrict__ u, const float* __restrict__ ctx_acc,
    const float* __restrict__ S, float* __restrict__ out)
{
    const int b = blockIdx.x, j = blockIdx.y, tid = threadIdx.x;
    const float invS = 1.0f / S[b];
    const float* ub = u + (size_t)b * T_SZ + j * 1024;
    float* wout = out + B_SZ * E_DIM + (size_t)b * T_SZ + j * 1024;
    #pragma unroll
    for (int it = 0; it < 4; ++it)
        wout[tid + it * 256] = ub[tid + it * 256] * invS;
    if (j == 0) {
        out[(size_t)b * E_DIM + tid]       = ctx_acc[b * E_DIM + tid] * invS;
        out[(size_t)b * E_DIM + 256 + tid] = ctx_acc[b * E_DIM + 256 + tid] * invS;
    }
}

extern "C" void kernel_launch(void* const* d_in, const int* in_sizes, int n_in,
                              void* d_out, int out_size, void* d_ws, size_t ws_size,
                              hipStream_t stream) {
    const float* enc   = (const float*)d_in[0];   // (64,4096,512)
    const float* dec   = (const float*)d_in[1];   // (64,512)
    const float* W_enc = (const float*)d_in[2];   // (512,256)
    const float* b_enc = (const float*)d_in[3];   // (256,)
    const float* W_dec = (const float*)d_in[4];   // (512,256)
    const float* v_att = (const float*)d_in[5];   // (256,)
    // d_in[6] = b_att: constant shift of all scores -> cancels in softmax.
    float* out = (float*)d_out;                   // [context 64*512 | weights 64*4096]

    // ws layout (bytes): Wt bf16 [0,262144) | dp [262144,327680)
    //                    | u [327680,1376256) | ctx_acc [1376256,1507328)
    //                    | S [1507328,1507584)
    char* ws = (char*)d_ws;
    unsigned short* Wt = (unsigned short*)(ws);
    float* dp          = (float*)(ws + 262144);
    float* u           = (float*)(ws + 327680);
    float* ctx_acc     = (float*)(ws + 1376256);
    float* S           = (float*)(ws + 1507328);

    prep_kernel<<<128, 256, 0, stream>>>(dec, W_enc, b_enc, W_dec, dp, Wt, ctx_acc, S);
    attn_main<<<B_SZ * SLICES, 512, 0, stream>>>(enc, Wt, dp, v_att, u, ctx_acc, S);
    finalize_kernel<<<dim3(B_SZ, 4), 256, 0, stream>>>(u, ctx_acc, S, out);
}

// Round 2
// 762.799 us; speedup vs baseline: 1.1714x; 1.1714x over previous
//
#include <hip/hip_runtime.h>
#include <hip/hip_bf16.h>

// Problem constants (match reference)
#define E_DIM 512
#define D_DIM 512
#define A_DIM 256
#define B_SZ  64
#define T_SZ  4096
#define TT    32              // t-rows per tile (double-buffered)
#define NTB   (T_SZ / TT)     // 128 tiles per b
#define TPB   16              // tiles per persistent block
#define SLICES (NTB / TPB)    // 8 slices per b -> grid 64*8 = 512 blocks
#define LDT   (E_DIM + 8)     // LDS row stride (bf16 elems)

typedef __bf16 bf16_t;
typedef bf16_t bf16x8 __attribute__((ext_vector_type(8)));
typedef float  f32x4  __attribute__((ext_vector_type(4)));

// round-to-nearest-even f32 -> bf16 bits
__device__ __forceinline__ unsigned short f2bf(float x) {
    union { float f; unsigned int u; } v; v.f = x;
    unsigned int u = v.u;
    return (unsigned short)((u + 0x7FFFu + ((u >> 16) & 1u)) >> 16);
}
__device__ __forceinline__ float bf2f(unsigned short h) {
    union { unsigned int u; float f; } v; v.u = ((unsigned int)h) << 16; return v.f;
}
__device__ __forceinline__ float tanh_fast(float x) {
    x = fminf(8.0f, fmaxf(-8.0f, x));            // exp(16) finite, avoids inf/inf
    float e = __expf(2.0f * x);
    return 1.0f - 2.0f * __builtin_amdgcn_rcpf(e + 1.0f);
}

// ---------------- Kernel 1: prep ----------------
// blocks 0..63   : dp[b][a] = b_enc[a] + sum_d dec[b][d]*W_dec[d][a]
//                  + zero ctx_acc[b][:] and S[b]
// blocks 64..127 : Wt[a][e] = bf16(W_enc[e][a])   (transposed, B-frag friendly)
__global__ __launch_bounds__(256) void prep_kernel(
    const float* __restrict__ dec, const float* __restrict__ W_enc,
    const float* __restrict__ b_enc, const float* __restrict__ W_dec,
    float* __restrict__ dp, unsigned short* __restrict__ Wt,
    float* __restrict__ ctx_acc, float* __restrict__ S)
{
    const int bid = blockIdx.x, tid = threadIdx.x;
    if (bid < B_SZ) {
        float s = b_enc[tid];
        const float* dr = dec + bid * D_DIM;
        #pragma unroll 8
        for (int d = 0; d < D_DIM; ++d)
            s = fmaf(dr[d], W_dec[d * A_DIM + tid], s);
        dp[bid * A_DIM + tid] = s;
        ctx_acc[bid * E_DIM + tid]       = 0.0f;
        ctx_acc[bid * E_DIM + 256 + tid] = 0.0f;
        if (tid == 0) S[bid] = 0.0f;
    } else {
        int base = (bid - B_SZ) * 2048;
        #pragma unroll
        for (int i = 0; i < 8; ++i) {
            int idx = base + tid + i * 256;       // idx = a*512 + e
            int a = idx >> 9, e = idx & 511;
            Wt[idx] = f2bf(W_enc[e * A_DIM + a]);
        }
    }
}

// ---------------- Kernel 2: main --------------------------------------------
// 512 blocks (p = b*8 + slice), 512 threads (8 waves), ~240 VGPR -> 1 block/CU.
// B (Wt slice) lives in REGISTERS for the whole block: K-loop has ZERO vmem,
// so vmcnt FIFO never entangles the MFMA stream with HBM prefetch.
// Depth-2 register prefetch (rA/rB), loop unrolled x2 with named reg sets.
#define LOADT(R, it_) do {                                                    \
    const float4* s_ = src0 + (size_t)(it_) * 4096;                           \
    _Pragma("unroll")                                                         \
    for (int j_ = 0; j_ < 8; ++j_) R[j_] = s_[tid + j_ * 512];                \
} while (0)

#define DRAINT(R, dst) do {                                                   \
    _Pragma("unroll")                                                         \
    for (int j_ = 0; j_ < 8; ++j_) {                                          \
        int idx_ = tid + j_ * 512;                                            \
        int rr_ = idx_ >> 7, cc_ = idx_ & 127;                                \
        ushort4 h_;                                                           \
        h_.x = f2bf(R[j_].x); h_.y = f2bf(R[j_].y);                           \
        h_.z = f2bf(R[j_].z); h_.w = f2bf(R[j_].w);                           \
        *(ushort4*)&(dst)[rr_ * LDT + cc_ * 4] = h_;                          \
    }                                                                         \
} while (0)

#define BODY(I, RFREE, RHELD, CUR)  do {                                      \
    f32x4 a00 = z4, a01 = z4, a10 = z4, a11 = z4;                             \
    _Pragma("unroll")                                                         \
    for (int ks = 0; ks < 16; ++ks) {                                         \
        const int ka = ks * 32 + q * 8;                                       \
        bf16x8 af0 = *(const bf16x8*)&tile[CUR][m16 * LDT + ka];              \
        bf16x8 af1 = *(const bf16x8*)&tile[CUR][(16 + m16) * LDT + ka];       \
        a00 = __builtin_amdgcn_mfma_f32_16x16x32_bf16(af0, breg0[ks], a00, 0, 0, 0); \
        a01 = __builtin_amdgcn_mfma_f32_16x16x32_bf16(af0, breg1[ks], a01, 0, 0, 0); \
        a10 = __builtin_amdgcn_mfma_f32_16x16x32_bf16(af1, breg0[ks], a10, 0, 0, 0); \
        a11 = __builtin_amdgcn_mfma_f32_16x16x32_bf16(af1, breg1[ks], a11, 0, 0, 0); \
    }                                                                         \
    _Pragma("unroll")                                                         \
    for (int rr = 0; rr < 4; ++rr) {                                          \
        float p0 = va0 * tanh_fast(a00[rr] + dv0)                             \
                 + va1 * tanh_fast(a01[rr] + dv1);                            \
        p0 += __shfl_xor(p0, 1); p0 += __shfl_xor(p0, 2);                     \
        p0 += __shfl_xor(p0, 4); p0 += __shfl_xor(p0, 8);                     \
        if (m16 == 0) spart[w][q * 4 + rr] = p0;                              \
        float p1 = va0 * tanh_fast(a10[rr] + dv0)                             \
                 + va1 * tanh_fast(a11[rr] + dv1);                            \
        p1 += __shfl_xor(p1, 1); p1 += __shfl_xor(p1, 2);                     \
        p1 += __shfl_xor(p1, 4); p1 += __shfl_xor(p1, 8);                     \
        if (m16 == 0) spart[w][16 + q * 4 + rr] = p1;                         \
    }                                                                         \
    __syncthreads();                          /* A: spart ready */            \
    if (tid < TT) {                                                           \
        float s_ = 0.f;                                                       \
        _Pragma("unroll")                                                     \
        for (int w8 = 0; w8 < 8; ++w8) s_ += spart[w8][tid];                  \
        float e_ = __expf(s_);                                                \
        uu[tid] = e_;                                                         \
        sS += e_;                                                             \
        u_out[(size_t)b * T_SZ + (size_t)(slice * TPB + (I)) * TT + tid] = e_;\
    }                                                                         \
    __syncthreads();                          /* B: uu ready */               \
    if ((I) + 2 < TPB) LOADT(RFREE, (I) + 2);                                 \
    _Pragma("unroll 8")                                                       \
    for (int t = 0; t < TT; ++t)                                              \
        c_acc = fmaf(uu[t], bf2f(tile[CUR][t * LDT + tid]), c_acc);           \
    if ((I) + 1 < TPB) DRAINT(RHELD, tile[(CUR) ^ 1]);                        \
    __syncthreads();                          /* C: buf nxt staged */         \
} while (0)

__global__ __launch_bounds__(512, 2) void attn_main(
    const float* __restrict__ enc, const unsigned short* __restrict__ Wt,
    const float* __restrict__ dpg, const float* __restrict__ vatt,
    float* __restrict__ u_out, float* __restrict__ ctx_acc,
    float* __restrict__ S)
{
    const int p = blockIdx.x;
    const int b = p >> 3, slice = p & 7;
    const int tid = threadIdx.x;

    __shared__ unsigned short tile[2][TT * LDT];  // 2 x 33,280 B
    __shared__ float spart[8][TT];
    __shared__ float uu[TT];
    __shared__ float dp_s[A_DIM];
    __shared__ float vv[A_DIM];

    if (tid < A_DIM) {
        dp_s[tid] = dpg[b * A_DIM + tid];
        vv[tid]   = vatt[tid];
    }

    const int w = tid >> 6, lane = tid & 63;
    const int m16 = lane & 15, q = lane >> 4;
    const f32x4 z4 = (f32x4){0.f, 0.f, 0.f, 0.f};

    // ---- B slice into registers, once per block (issued first in FIFO) ----
    const unsigned short* WtW = Wt + (size_t)(w * 32) * E_DIM;
    bf16x8 breg0[16], breg1[16];
    #pragma unroll
    for (int ks = 0; ks < 16; ++ks) {
        breg0[ks] = *(const bf16x8*)&WtW[m16 * E_DIM + ks * 32 + q * 8];
        breg1[ks] = *(const bf16x8*)&WtW[(16 + m16) * E_DIM + ks * 32 + q * 8];
    }

    // base of this block's 16-tile stream: contiguous 8 MB of enc
    const float4* src0 = (const float4*)(enc +
        ((size_t)b * T_SZ + (size_t)slice * TPB * TT) * E_DIM);

    // ---- prologue: prefetch tiles 0 and 1; stage tile 0 ----
    float4 rA[8], rB[8];
    LOADT(rA, 0);
    LOADT(rB, 1);
    DRAINT(rA, tile[0]);
    __syncthreads();

    float va0, va1, dv0, dv1;
    {
        int a0 = w * 32 + m16;
        va0 = vv[a0]; va1 = vv[a0 + 16];
        dv0 = dp_s[a0]; dv1 = dp_s[a0 + 16];
    }

    float c_acc = 0.0f;   // context partial for col e = tid
    float sS    = 0.0f;   // exp-sum partial (tid < 32 only)

    #pragma unroll 1
    for (int i2 = 0; i2 < TPB; i2 += 2) {
        BODY(i2,     rA, rB, 0);   // even tile: buf0; holds tile i2+1 in rB
        BODY(i2 + 1, rB, rA, 1);   // odd tile:  buf1; holds tile i2+2 in rA
    }

    // one atomic per thread for context, one per block for the denom
    atomicAdd(&ctx_acc[(size_t)b * E_DIM + tid], c_acc);
    if (w == 0) {
        sS += __shfl_xor(sS, 1);  sS += __shfl_xor(sS, 2);
        sS += __shfl_xor(sS, 4);  sS += __shfl_xor(sS, 8);
        sS += __shfl_xor(sS, 16); sS += __shfl_xor(sS, 32);
        if (lane == 0) atomicAdd(&S[b], sS);
    }
}

// ---------------- Kernel 3: finalize (pure scaling) --------------------------
__global__ __launch_bounds__(256) void finalize_kernel(
    const float* __restrict__ u, const float* __restrict__ ctx_acc,
    const float* __restrict__ S, float* __restrict__ out)
{
    const int b = blockIdx.x, j = blockIdx.y, tid = threadIdx.x;
    const float invS = 1.0f / S[b];
    const float* ub = u + (size_t)b * T_SZ + j * 1024;
    float* wout = out + B_SZ * E_DIM + (size_t)b * T_SZ + j * 1024;
    #pragma unroll
    for (int it = 0; it < 4; ++it)
        wout[tid + it * 256] = ub[tid + it * 256] * invS;
    if (j == 0) {
        out[(size_t)b * E_DIM + tid]       = ctx_acc[b * E_DIM + tid] * invS;
        out[(size_t)b * E_DIM + 256 + tid] = ctx_acc[b * E_DIM + 256 + tid] * invS;
    }
}

extern "C" void kernel_launch(void* const* d_in, const int* in_sizes, int n_in,
                              void* d_out, int out_size, void* d_ws, size_t ws_size,
                              hipStream_t stream) {
    const float* enc   = (const float*)d_in[0];   // (64,4096,512)
    const float* dec   = (const float*)d_in[1];   // (64,512)
    const float* W_enc = (const float*)d_in[2];   // (512,256)
    const float* b_enc = (const float*)d_in[3];   // (256,)
    const float* W_dec = (const float*)d_in[4];   // (512,256)
    const float* v_att = (const float*)d_in[5];   // (256,)
    // d_in[6] = b_att: constant shift of all scores -> cancels in softmax.
    float* out = (float*)d_out;                   // [context 64*512 | weights 64*4096]

    // ws layout (bytes): Wt bf16 [0,262144) | dp [262144,327680)
    //                    | u [327680,1376256) | ctx_acc [1376256,1507328)
    //                    | S [1507328,1507584)
    char* ws = (char*)d_ws;
    unsigned short* Wt = (unsigned short*)(ws);
    float* dp          = (float*)(ws + 262144);
    float* u           = (float*)(ws + 327680);
    float* ctx_acc     = (float*)(ws + 1376256);
    float* S           = (float*)(ws + 1507328);

    prep_kernel<<<128, 256, 0, stream>>>(dec, W_enc, b_enc, W_dec, dp, Wt, ctx_acc, S);
    attn_main<<<B_SZ * SLICES, 512, 0, stream>>>(enc, Wt, dp, v_att, u, ctx_acc, S);
    finalize_kernel<<<dim3(B_SZ, 4), 256, 0, stream>>>(u, ctx_acc, S, out);
}